// Round 9
// baseline (299.092 us; speedup 1.0000x reference)
//
#include <hip/hip_runtime.h>
#include <hip/hip_cooperative_groups.h>
#include <cstdint>

namespace cg = cooperative_groups;

#define BATCH   8192
#define KDIM    256
#define HID     64
#define NODES   255
#define NPG     16    // nodes per block group (fused phase)
#define NPRM    16320 // 255*64

typedef unsigned short u16;
typedef unsigned int u32;
typedef short bf16x8 __attribute__((ext_vector_type(8)));
typedef float f32x16 __attribute__((ext_vector_type(16)));

// ---- helpers ---------------------------------------------------------------

__device__ __forceinline__ u32 f2bf(float f) {
  u32 u = __float_as_uint(f);
  return (u + 0x7FFFu + ((u >> 16) & 1u)) >> 16;
}

__device__ __forceinline__ void gld_lds16(const void* g, void* l) {
  // async global->LDS, 16B/lane; LDS dest = wave-uniform base + lane*16
  typedef __attribute__((address_space(1))) void* gp_t;
  typedef __attribute__((address_space(3))) void* lp_t;
  gp_t gp = reinterpret_cast<gp_t>(reinterpret_cast<uintptr_t>(g));
  lp_t lp = reinterpret_cast<lp_t>(static_cast<u32>(reinterpret_cast<uintptr_t>(l)));
  __builtin_amdgcn_global_load_lds(gp, lp, 16, 0, 0);
}

// ---- R17: single cooperative mega-kernel ------------------------------------
// R16 post-mortem: occupancy 19->27% made fused WORSE (72 vs 64.4) with 3x
// WRITE_SIZE (scratch/spill traffic) — occupancy lever falsified; every
// scheduling lever on the fused wall is now nulled. Meanwhile total = fused
// + 87±3us across ALL rounds while cvt+tree BW floors are ~13us — the gap
// has never been measured (top-5 only shows fused). This round: merge the 3
// kernels into ONE cooperative kernel (bodies VERBATIM from verified-passing
// rounds; only glue is new):
//  - grid 512 = exactly the measured 2-blocks/CU residency of the fused
//    config (and tree needs exactly 512 blocks).
//  - phase loops strided by gridDim.x tolerate any co-resident grid size.
//  - __threadfence() + grid.sync() between phases (device-scope visibility
//    across XCD L2s, per G16).
//  - LDS union: max(fused 73.7KB, cvt 33KB, tree 16.4KB) = 73728B, same
//    footprint as before.
// Readout: mega dur = TRUE cvt+fused+tree sum (the missing decomposition);
// any launch-gap/sync savings show in total.

__global__ __launch_bounds__(256, 2) void mega_kernel(
    const float* __restrict__ x, const float* __restrict__ w1,
    const float* __restrict__ b1, const float* __restrict__ w2,
    const float* __restrict__ b2, const float* __restrict__ leaf,
    u16* __restrict__ xpack, u16* __restrict__ w1pk,
    float* __restrict__ b1p, float* __restrict__ w2p,
    float* __restrict__ no_t, float* __restrict__ out)
{
  cg::grid_group grid = cg::this_grid();

  __shared__ __align__(16) union ShU {
    struct { u16 sW[2][16384]; float sW2[NPG * 64]; float sB1[NPG * 64]; } f;
    u16 cx[32 * 268];      // cvt x-transpose
    u16 cw[64 * 260];      // cvt w1-transpose
    float tp[16][257];     // tree staging
  } sh;

  const int tid  = threadIdx.x;
  const int lane = tid & 63;
  const int wv   = tid >> 6;
  const int l31  = lane & 31;
  const int hl   = lane >> 5;

  // ============ phase 1: convert + pack (cvt body VERBATIM, blk looped) =====
  for (int blk = blockIdx.x; blk < 639; blk += gridDim.x) {
    if (blk < 256) {
      u16* sT = sh.cx;
      const float* xs = x + (size_t)blk * 32 * KDIM;
#pragma unroll
      for (int j = 0; j < 8; ++j) {
        int idx = j * 256 + tid;
        float4 v = ((const float4*)xs)[idx];
        int row = idx >> 6, f4 = idx & 63;
        *(u32*)&sT[row * 268 + f4 * 4]     = f2bf(v.x) | (f2bf(v.y) << 16);
        *(u32*)&sT[row * 268 + f4 * 4 + 2] = f2bf(v.z) | (f2bf(v.w) << 16);
      }
      __syncthreads();
#pragma unroll
      for (int j = 0; j < 4; ++j) {
        int d = j * 256 + tid;               // granule: ks*64 + hl*32 + l31
        int ks = d >> 6, hh = (d >> 5) & 1, ll = d & 31;
        const u16* s8 = &sT[ll * 268 + ks * 16 + hh * 8];
        u32 a = *(const u32*)s8, b = *(const u32*)(s8 + 2);
        u32 c = *(const u32*)(s8 + 4), e = *(const u32*)(s8 + 6);
        uint4 o = {a, b, c, e};
        ((uint4*)xpack)[(size_t)blk * 1024 + d] = o;
      }
    } else if (blk < 511) {
      u16* sT = sh.cw;
      const int node = blk - 256;
      const float* src = w1 + (size_t)node * (HID * KDIM);
#pragma unroll
      for (int r = 0; r < 16; ++r) {
        int idx = r * 256 + tid;
        float4 v = ((const float4*)src)[idx];
        int h = idx >> 6, f4 = idx & 63;
        uint2 o;
        o.x = f2bf(v.x) | (f2bf(v.y) << 16);
        o.y = f2bf(v.z) | (f2bf(v.w) << 16);
        *(uint2*)&sT[h * 260 + f4 * 4] = o;
      }
      __syncthreads();
      u16* dst = w1pk + (size_t)node * (HID * KDIM);
#pragma unroll
      for (int r = 0; r < 8; ++r) {
        int g = r * 256 + tid;
        int kb = g >> 6, h = g & 63;
        const u16* s8 = &sT[h * 260 + kb * 8];
        uint2 lo = *(const uint2*)s8;
        uint2 hi = *(const uint2*)(s8 + 4);
        uint4 o = {lo.x, lo.y, hi.x, hi.y};
        ((uint4*)dst)[g] = o;
      }
    } else {
      int i2 = (blk - 511) * 256 + tid;
      if (i2 < 2 * NPRM) {
        int a = i2 >= NPRM;
        int j = a ? i2 - NPRM : i2;
        int reg = j & 15, rt = (j >> 4) & 1, hh = (j >> 5) & 1, node = j >> 6;
        int h = rt * 32 + (reg & 3) + 8 * (reg >> 2) + 4 * hh;
        float v = (a ? b1 : w2)[node * 64 + h];
        (a ? b1p : w2p)[j] = v;
      }
    }
    __syncthreads();   // LDS reuse across jobs
  }

  __threadfence();
  grid.sync();

  // ============ phase 2: fused MLP (R14 body, plain __syncthreads) ==========
  for (int fb = blockIdx.x; fb < 512; fb += gridDim.x) {
    const int bx = fb & 31;          // col-block   (was blockIdx.x in 32x16)
    const int by = fb >> 5;          // node-group  (was blockIdx.y)
    const int nbase = by * NPG;

    auto stage_node = [&](int nodeIdx, int bufIdx) {
      const u16* base = w1pk + (size_t)nodeIdx * (HID * KDIM);
      char* lb = (char*)(&sh.f.sW[bufIdx][0]);
#pragma unroll
      for (int j = 0; j < 8; ++j) {
        int s = j * 256 + tid;
        gld_lds16(base + s * 8, lb + s * 16);
      }
    };

    stage_node(nbase, 0);
    gld_lds16(w2p + (size_t)nbase * 64 + tid * 4, (char*)sh.f.sW2 + tid * 16);
    gld_lds16(b1p + (size_t)nbase * 64 + tid * 4, (char*)sh.f.sB1 + tid * 16);

    // x fragments: 2 col-tiles of 32 x 16 ks, coalesced
    const int ctile0 = bx * 8 + wv * 2;
    bf16x8 xf[2][16];
#pragma unroll
    for (int ct = 0; ct < 2; ++ct) {
      const u16* src = xpack + ((size_t)(ctile0 + ct) * 16) * 512 + lane * 8;
#pragma unroll
      for (int ks = 0; ks < 16; ++ks)
        xf[ct][ks] = *(const bf16x8*)(src + ks * 512);
    }

    const u32 abase = (u32)(hl * 64 + l31) * 16u;

    __syncthreads();  // drains prologue staging vmcnt
    int buf = 0;

    for (int i = 0; i < NPG; ++i) {
      const int node = nbase + i;

      if (i + 1 < NPG) stage_node(nbase + i + 1, buf ^ 1);

      // acc init from bias (fold) — verified in R14
      f32x16 acc00, acc01, acc10, acc11;
      {
        const int o0 = i * 64 + hl * 32;
#pragma unroll
        for (int qd = 0; qd < 4; ++qd) {
          float4 b0  = *(const float4*)&sh.f.sB1[o0 + qd * 4];        // ht=0
          float4 b1q = *(const float4*)&sh.f.sB1[o0 + 16 + qd * 4];   // ht=1
#pragma unroll
          for (int e = 0; e < 4; ++e) {
            acc00[qd * 4 + e] = (&b0.x)[e];
            acc01[qd * 4 + e] = (&b0.x)[e];
            acc10[qd * 4 + e] = (&b1q.x)[e];
            acc11[qd * 4 + e] = (&b1q.x)[e];
          }
        }
      }

      const char* sw = (const char*)&sh.f.sW[buf][0] + abase;
      __builtin_amdgcn_s_setprio(1);
#pragma unroll
      for (int ks = 0; ks < 16; ++ks) {
        bf16x8 a0 = *(const bf16x8*)(sw + ks * 2048);        // ht=0
        bf16x8 a1 = *(const bf16x8*)(sw + ks * 2048 + 512);  // ht=1
        acc00 = __builtin_amdgcn_mfma_f32_32x32x16_bf16(a0, xf[0][ks], acc00, 0, 0, 0);
        acc01 = __builtin_amdgcn_mfma_f32_32x32x16_bf16(a0, xf[1][ks], acc01, 0, 0, 0);
        acc10 = __builtin_amdgcn_mfma_f32_32x32x16_bf16(a1, xf[0][ks], acc10, 0, 0, 0);
        acc11 = __builtin_amdgcn_mfma_f32_32x32x16_bf16(a1, xf[1][ks], acc11, 0, 0, 0);
      }
      __builtin_amdgcn_s_setprio(0);

      // epilogue: full logit, wave-local (bias already in acc)
      float p0 = 0.f, p1 = 0.f;
#pragma unroll
      for (int qd = 0; qd < 4; ++qd) {
        int o = i * 64 + hl * 32 + qd * 4;
        float4 w0  = *(const float4*)&sh.f.sW2[o];        // ht=0
        float4 w1q = *(const float4*)&sh.f.sW2[o + 16];   // ht=1
#pragma unroll
        for (int e = 0; e < 4; ++e) {
          int r = qd * 4 + e;
          p0 += fmaxf(acc00[r], 0.f) * (&w0.x)[e];
          p1 += fmaxf(acc01[r], 0.f) * (&w0.x)[e];
          p0 += fmaxf(acc10[r], 0.f) * (&w1q.x)[e];
          p1 += fmaxf(acc11[r], 0.f) * (&w1q.x)[e];
        }
      }
      p0 += __shfl_xor(p0, 32);
      p1 += __shfl_xor(p1, 32);

      if (node < NODES) {
        float pv = hl ? p1 : p0;
        float sig = 1.0f / (1.0f + expf(-(pv + b2[node])));
        no_t[(size_t)node * BATCH + bx * 256 + wv * 64 + lane] = sig;
      }

      __syncthreads();   // conservative full drain (verified R10 behavior)
      buf ^= 1;
    }
  }

  __threadfence();
  grid.sync();

  // ============ phase 3: tree traversal (body VERBATIM, tb looped) ==========
  for (int tb = blockIdx.x; tb < 512; tb += gridDim.x) {
    const int bbase = tb * 16;

    for (int i = tid; i < NODES * 16; i += 256) {
      int n = i >> 4, r = i & 15;
      sh.tp[r][n] = no_t[(size_t)n * BATCH + bbase + r];
    }
    __syncthreads();

    float4 lw = ((const float4*)leaf)[lane];

    float* h_out  = out;
    float* pp_out = out + 8192;                            // [8192][256]
    float* no_out = out + 8192 + 8192 * 256;               // [8192][255]
    float* nr_out = out + 8192 + 8192 * 256 + 8192 * (size_t)NODES;  // [8192][255]

    for (int j = 0; j < 4; ++j) {
      const int r = wv * 4 + j;
      const int b = bbase + r;
      const float* pr = sh.tp[r];
      float* nr_b = nr_out + (size_t)b * NODES;

      float rc = 1.f;
#pragma unroll
      for (int L = 0; L < 6; ++L) {
        if (lane < (1 << L)) nr_b[(1 << L) - 1 + lane] = rc;
        float par = __shfl(rc, lane >> 1);
        float pv = pr[(1 << L) - 1 + (lane >> 1)];
        rc = par * ((lane & 1) ? pv : (1.f - pv));
      }
      nr_b[63 + lane] = rc;
      float p6 = pr[63 + lane];
      float r7a = rc * (1.f - p6), r7b = rc * p6;
      nr_b[127 + 2 * lane]     = r7a;
      nr_b[127 + 2 * lane + 1] = r7b;
      float p7a = pr[127 + 2 * lane], p7b = pr[127 + 2 * lane + 1];
      float4 pp;
      pp.x = r7a * (1.f - p7a);
      pp.y = r7a * p7a;
      pp.z = r7b * (1.f - p7b);
      pp.w = r7b * p7b;
      ((float4*)(pp_out + (size_t)b * 256))[lane] = pp;

      float* no_b = no_out + (size_t)b * NODES;
#pragma unroll
      for (int k = 0; k < 4; ++k) {
        int n = lane + 64 * k;
        if (n < NODES) no_b[n] = pr[n];
      }

      float hacc = pp.x * lw.x + pp.y * lw.y + pp.z * lw.z + pp.w * lw.w;
      hacc += __shfl_xor(hacc, 1);
      hacc += __shfl_xor(hacc, 2);
      hacc += __shfl_xor(hacc, 4);
      hacc += __shfl_xor(hacc, 8);
      hacc += __shfl_xor(hacc, 16);
      hacc += __shfl_xor(hacc, 32);
      if (lane == 0) h_out[b] = hacc;
    }
    __syncthreads();   // LDS reuse if this block loops
  }
}

// ---- launcher --------------------------------------------------------------

extern "C" void kernel_launch(void* const* d_in, const int* in_sizes, int n_in,
                              void* d_out, int out_size, void* d_ws, size_t ws_size,
                              hipStream_t stream) {
  const float* x    = (const float*)d_in[0];
  const float* w1   = (const float*)d_in[1];
  const float* b1   = (const float*)d_in[2];
  const float* w2   = (const float*)d_in[3];
  const float* b2   = (const float*)d_in[4];
  const float* leaf = (const float*)d_in[5];
  float* out = (float*)d_out;

  // ws: xpack 4MB | w1pk 8MB (256-node pad; node 255 poison-but-finite) |
  //     w2p 64KB | b1p 64KB | no_t 8MB
  char* ws = (char*)d_ws;
  u16*   xpack = (u16*)ws;
  u16*   w1pk  = (u16*)(ws + (size_t)4194304);
  float* w2p   = (float*)(ws + (size_t)12582912);
  float* b1p   = (float*)(ws + (size_t)12648192);
  float* no_t  = (float*)(ws + (size_t)12713472);

  // co-resident grid: measured 2 blocks/CU for this config -> 512; query to
  // be safe (phase loops tolerate any co-resident size).
  int maxBlk = 0;
  (void)hipOccupancyMaxActiveBlocksPerMultiprocessor(
      &maxBlk, reinterpret_cast<const void*>(mega_kernel), 256, 0);
  int grid = maxBlk * 256;
  if (grid > 512) grid = 512;
  if (grid < 256) grid = 256;   // fallback; 1/CU is still co-resident

  void* args[12] = {
    (void*)&x, (void*)&w1, (void*)&b1, (void*)&w2, (void*)&b2, (void*)&leaf,
    (void*)&xpack, (void*)&w1pk, (void*)&b1p, (void*)&w2p, (void*)&no_t,
    (void*)&out
  };
  hipLaunchCooperativeKernel(reinterpret_cast<const void*>(mega_kernel),
                             dim3(grid), dim3(256), args, 0, stream);
}